// Round 4
// baseline (209.480 us; speedup 1.0000x reference)
//
#include <hip/hip_runtime.h>
#include <stdint.h>

// ---------------------------------------------------------------------------
// CausalSelfAttention (B=2, T=2048, D=1024, H=16, Dh=64), fp32 in/out.
// cvt(fp32->bf16) -> QKV gemm (bf16 MFMA) -> flash attn (32x32 swapped,
// in-block KV-split pairs, K direct from L2) -> out gemm.
// ---------------------------------------------------------------------------

typedef unsigned short u16;
typedef __attribute__((ext_vector_type(8)))  __bf16 bf16x8;   // 4 VGPR MFMA A/B frag
typedef __attribute__((ext_vector_type(4)))  float  f32x4;    // 16x16 C/D frag
typedef __attribute__((ext_vector_type(16))) float  f32x16;   // 32x32 C/D frag
typedef __attribute__((ext_vector_type(4)))  float  float4v;
typedef __attribute__((ext_vector_type(4)))  unsigned short u16x4;
typedef __attribute__((ext_vector_type(4)))  unsigned int   u32x4;
typedef __attribute__((ext_vector_type(8)))  short  short8;   // raw 16B load

#define BB 2
#define TT 2048
#define DD 1024
#define HH 16
#define DH 64
#define MM (BB*TT)          // 4096 rows

static __device__ __forceinline__ u16 f2bf(float f) {
    uint32_t u = __builtin_bit_cast(uint32_t, f);
    u += 0x7FFFu + ((u >> 16) & 1u);          // round-to-nearest-even
    return (u16)(u >> 16);
}

// pack two f32 -> one u32 of two bf16 (low = a, high = b)
static __device__ __forceinline__ unsigned cvt_pk_bf16(float a, float b) {
    unsigned r;
    asm("v_cvt_pk_bf16_f32 %0, %1, %2" : "=v"(r) : "v"(a), "v"(b));
    return r;
}

// global(16B per lane) -> LDS direct copy (wave-uniform dst base + lane*16).
static __device__ __forceinline__ void load_lds16(const u16* g, const u16* lds_base) {
    __builtin_amdgcn_global_load_lds(
        (const __attribute__((address_space(1))) void*)(uintptr_t)g,
        (__attribute__((address_space(3)))  void*)(uint32_t)(uintptr_t)lds_base,
        16u, 0, 0u);
}

static __device__ __forceinline__ f32x4 mfma16(bf16x8 a, bf16x8 b, f32x4 c) {
    return __builtin_amdgcn_mfma_f32_16x16x32_bf16(a, b, c, 0, 0, 0);
}
static __device__ __forceinline__ f32x16 mfma32(bf16x8 a, bf16x8 b, f32x16 c) {
    return __builtin_amdgcn_mfma_f32_32x32x16_bf16(a, b, c, 0, 0, 0);
}

// balanced trees over the 32 per-lane score registers (depth ~5, not 31)
static __device__ __forceinline__ float tree_max32(const f32x16& a, const f32x16& b) {
    float m[16];
#pragma unroll
    for (int r = 0; r < 16; ++r) m[r] = fmaxf(a[r], b[r]);
#pragma unroll
    for (int off = 8; off; off >>= 1)
#pragma unroll
        for (int r = 0; r < off; ++r) m[r] = fmaxf(m[r], m[r + off]);
    return m[0];
}
static __device__ __forceinline__ float tree_sum32(const f32x16& a, const f32x16& b) {
    float m[16];
#pragma unroll
    for (int r = 0; r < 16; ++r) m[r] = a[r] + b[r];
#pragma unroll
    for (int off = 8; off; off >>= 1)
#pragma unroll
        for (int r = 0; r < off; ++r) m[r] += m[r + off];
    return m[0];
}

// ------------------------------ fp32 -> bf16 -------------------------------
__global__ __launch_bounds__(256) void cvt_kernel(const float* __restrict__ src,
                                                  u16* __restrict__ dst, int n4) {
    int i = blockIdx.x * blockDim.x + threadIdx.x;
    int stride = gridDim.x * blockDim.x;
    for (; i < n4; i += stride) {
        float4v v = ((const float4v*)src)[i];
        u16x4 o;
        o[0] = f2bf(v[0]); o[1] = f2bf(v[1]); o[2] = f2bf(v[2]); o[3] = f2bf(v[3]);
        ((u16x4*)dst)[i] = o;
    }
}

// four matrices in one launch (z = blockIdx.y selects)
__global__ __launch_bounds__(256) void cvt4_kernel(const float* __restrict__ s0,
        const float* __restrict__ s1, const float* __restrict__ s2,
        const float* __restrict__ s3, u16* __restrict__ d0, u16* __restrict__ d1,
        u16* __restrict__ d2, u16* __restrict__ d3, int n4) {
    const int z = blockIdx.y;
    const float* src = (z == 0) ? s0 : (z == 1) ? s1 : (z == 2) ? s2 : s3;
    u16* dst = (z == 0) ? d0 : (z == 1) ? d1 : (z == 2) ? d2 : d3;
    int i = blockIdx.x * blockDim.x + threadIdx.x;
    int stride = gridDim.x * blockDim.x;
    for (; i < n4; i += stride) {
        float4v v = ((const float4v*)src)[i];
        u16x4 o;
        o[0] = f2bf(v[0]); o[1] = f2bf(v[1]); o[2] = f2bf(v[2]); o[3] = f2bf(v[3]);
        ((u16x4*)dst)[i] = o;
    }
}

// ------------------------- GEMM  C = A * W^T + bias ------------------------
// A: [M,K] bf16 row-major. W: [z][N,K] bf16 row-major (z = blockIdx.z).
// OUTF32==0: bf16 out at outb + z*M*N ; OUTF32==1: f32 out to outf.
// 128x128 tile, BK=32, 256 threads (4 waves, 2x2 of 64x64), m97 structure.
template<int OUTF32>
__global__ __launch_bounds__(256) void gemm_nt(const u16* __restrict__ A,
        const u16* __restrict__ W,
        const float* __restrict__ b0, const float* __restrict__ b1,
        const float* __restrict__ b2,
        u16* __restrict__ outb, float* __restrict__ outf,
        int M, int N, int K) {
    __shared__ alignas(16) u16 As[128 * 32];
    __shared__ alignas(16) u16 Bs[128 * 32];

    const int tid  = threadIdx.x;
    const int wave = tid >> 6, lane = tid & 63;
    const int lr = lane & 15, lg = lane >> 4;
    const int wr = wave >> 1, wc = wave & 1;
    const int z  = blockIdx.z;
    const int m0 = blockIdx.x * 128;
    const int n0 = blockIdx.y * 128;

    const u16* Wz = W + (size_t)z * N * K;
    const float* bias = (z == 0) ? b0 : (z == 1) ? b1 : b2;

    f32x4 acc[4][4];
#pragma unroll
    for (int m = 0; m < 4; ++m)
#pragma unroll
        for (int n = 0; n < 4; ++n) acc[m][n] = (f32x4){0.f, 0.f, 0.f, 0.f};

    for (int k0 = 0; k0 < K; k0 += 32) {
        __syncthreads();
#pragma unroll
        for (int it = 0; it < 2; ++it) {
            int c = it * 256 + tid;
            int row = c >> 2, cc = (c & 3) * 8;
            const u16* gA = A  + (size_t)(m0 + row) * K + k0 + cc;
            const u16* gB = Wz + (size_t)(n0 + row) * K + k0 + cc;
            load_lds16(gA, As + (size_t)(it * 256 + wave * 64) * 8);
            load_lds16(gB, Bs + (size_t)(it * 256 + wave * 64) * 8);
        }
        __syncthreads();

        bf16x8 af[4], bfm[4];
#pragma unroll
        for (int m = 0; m < 4; ++m)
            af[m] = *(const bf16x8*)&As[(wr * 64 + m * 16 + lr) * 32 + lg * 8];
#pragma unroll
        for (int n = 0; n < 4; ++n)
            bfm[n] = *(const bf16x8*)&Bs[(wc * 64 + n * 16 + lr) * 32 + lg * 8];
#pragma unroll
        for (int m = 0; m < 4; ++m)
#pragma unroll
            for (int n = 0; n < 4; ++n)
                acc[m][n] = mfma16(af[m], bfm[n], acc[m][n]);
    }

#pragma unroll
    for (int n = 0; n < 4; ++n) {
        int col = n0 + wc * 64 + n * 16 + lr;
        float bv = bias[col];
#pragma unroll
        for (int m = 0; m < 4; ++m) {
            int row = m0 + wr * 64 + m * 16 + lg * 4;
#pragma unroll
            for (int r = 0; r < 4; ++r) {
                float v = acc[m][n][r] + bv;
                if (OUTF32 == 0)
                    outb[(size_t)z * M * N + (size_t)(row + r) * N + col] = f2bf(v);
                else
                    outf[(size_t)(row + r) * N + col] = v;
            }
        }
    }
}

// ------------------------------- attention ---------------------------------
// grid (32, 32): qb = 31 - blockIdx.x, 64 q rows per block; bh = blockIdx.y.
// 4 warps = 2 pairs. pair pa (= wave>>1) processes tiles t = 2s+pa (KV-split);
// warp's q half = wave&1. Each pair keeps private online-softmax state; one
// in-LDS merge at the end (paired warps own the SAME q columns -> lane-aligned).
// Swapped-operand 32x32 MFMA: S^T = K.Q^T (lane owns one q col), K loaded
// DIRECTLY from global (L2-hot: 16 blocks share each bh's 256KB K panel).
// V transposed into per-pair LDS buffer. 2 barriers per step.
__global__ __launch_bounds__(256) void attn_kernel(const u16* __restrict__ Qb,
        const u16* __restrict__ Kb, const u16* __restrict__ Vb,
        u16* __restrict__ Yb) {
    // pool: loop phase = Vt[2][64*72] u16 (18432 B);
    // merge phase overlay = Ob f32[2][64*33] + Ml f32[2][64]  (17408 B)
    __shared__ alignas(16) u16 pool[9216];

    const int tid  = threadIdx.x;
    const int wave = tid >> 6, lane = tid & 63;
    const int lq = lane & 31, hi = lane >> 5;
    const int pa   = wave >> 1;               // 0: even tiles, 1: odd tiles
    const int half = wave & 1;                // q half within the block
    const int qb = 31 - blockIdx.x;           // longest blocks dispatch first
    const int bh = blockIdx.y;
    const int b = bh >> 4, h = bh & 15;
    const size_t rb = (size_t)b * TT;
    const int hoff = h * DH;
    const int q0w = qb * 64 + half * 32;      // warp q base (within this b)
    const int nk = qb + 1;                    // 64-key tiles needed by block
    const int steps = (nk + 1) >> 1;

    u16* Vtp = pool + pa * (64 * 72);         // this pair's V^T buffer
    const u16* Kbh = Kb + rb * DD + hoff;
    const u16* Vbh = Vb + rb * DD + hoff;

    // V staging: this wave covers all 64 keys (lane=key) x 32 d (half picks)
    const int vkey = lane;
    const int vd0  = half * 32;

    // Q fragments (B-operand): col=lane&31=q, k=(lane>>5)*8+j ; 4 chunks of 16
    bf16x8 qf[4];
    {
        const u16* qrow = Qb + (rb + q0w + lq) * DD + hoff + hi * 8;
#pragma unroll
        for (int kc = 0; kc < 4; ++kc) qf[kc] = *(const bf16x8*)(qrow + kc * 16);
    }

    f32x16 o0 = {}, o1 = {};
    float m_i = -1e30f, l_i = 0.f;
    const float cexp = 0.18033688011f;        // 0.125 * log2(e)

    for (int s = 0; s < steps; ++s) {
        const int t = 2 * s + pa;             // this pair's tile this step

        // ---- stage V^T for tile t into this pair's buffer (t==nk harmless)
        {
            const u16* vrow = Vbh + (size_t)(t * 64 + vkey) * DD + vd0;
            short8 v0 = *(const short8*)(vrow);
            short8 v1 = *(const short8*)(vrow + 8);
            short8 v2 = *(const short8*)(vrow + 16);
            short8 v3 = *(const short8*)(vrow + 24);
#pragma unroll
            for (int j = 0; j < 8; ++j) {
                Vtp[(vd0 +      j) * 72 + vkey] = (u16)v0[j];
                Vtp[(vd0 +  8 + j) * 72 + vkey] = (u16)v1[j];
                Vtp[(vd0 + 16 + j) * 72 + vkey] = (u16)v2[j];
                Vtp[(vd0 + 24 + j) * 72 + vkey] = (u16)v3[j];
            }
        }
        __syncthreads();

        if (t < nk) {
            // S^T[key][q] = K.Q^T ; K A-frags straight from global (L2-hot)
            const u16* Kt = Kbh + (size_t)(t * 64 + lq) * DD + hi * 8;
            f32x16 st0 = {}, st1 = {};
#pragma unroll
            for (int kc = 0; kc < 4; ++kc) {
                bf16x8 k0 = *(const bf16x8*)(Kt + kc * 16);
                st0 = mfma32(k0, qf[kc], st0);
            }
#pragma unroll
            for (int kc = 0; kc < 4; ++kc) {
                bf16x8 k1 = *(const bf16x8*)(Kt + (size_t)32 * DD + kc * 16);
                st1 = mfma32(k1, qf[kc], st1);
            }

            // causal mask on raw scores (scale folded into exp2 constant)
            if (t * 64 + 63 > q0w) {
                const int qrel = q0w + lq - t * 64;
#pragma unroll
                for (int r = 0; r < 16; ++r) {
                    int key = (r & 3) + 8 * (r >> 2) + 4 * hi;
                    if (key      > qrel) st0[r] = -1e30f;
                    if (key + 32 > qrel) st1[r] = -1e30f;
                }
            }

            // online softmax, in-lane tree reduces
            float pm = tree_max32(st0, st1);
            pm = fmaxf(pm, __shfl_xor(pm, 32));
            if (!__all(pm - m_i <= 44.3614f)) {      // defer-max (T13)
                const float mnew  = fmaxf(m_i, pm);
                const float alpha = __builtin_amdgcn_exp2f((m_i - mnew) * cexp);
                l_i *= alpha;
#pragma unroll
                for (int r = 0; r < 16; ++r) { o0[r] *= alpha; o1[r] *= alpha; }
                m_i = mnew;
            }
#pragma unroll
            for (int r = 0; r < 16; ++r) {
                st0[r] = __builtin_amdgcn_exp2f((st0[r] - m_i) * cexp);
                st1[r] = __builtin_amdgcn_exp2f((st1[r] - m_i) * cexp);
            }
            float rs = tree_sum32(st0, st1);
            rs += __shfl_xor(rs, 32);
            l_i += rs;

            // P^T -> B-operand frags: cvt_pk pairs + permlane32_swap (T12)
            bf16x8 pb[4];
#pragma unroll
            for (int ks = 0; ks < 4; ++ks) {
                const f32x16& sb = (ks < 2) ? st0 : st1;
                const int base = 8 * (ks & 1);
                unsigned c0 = cvt_pk_bf16(sb[base + 0], sb[base + 1]);
                unsigned c1 = cvt_pk_bf16(sb[base + 2], sb[base + 3]);
                unsigned c2 = cvt_pk_bf16(sb[base + 4], sb[base + 5]);
                unsigned c3 = cvt_pk_bf16(sb[base + 6], sb[base + 7]);
                asm volatile("v_permlane32_swap_b32 %0, %1" : "+v"(c0), "+v"(c2));
                asm volatile("v_permlane32_swap_b32 %0, %1" : "+v"(c1), "+v"(c3));
                u32x4 w; w[0] = c0; w[1] = c1; w[2] = c2; w[3] = c3;
                pb[ks] = __builtin_bit_cast(bf16x8, w);
            }

            // O^T += V^T . P^T : A=V^T (row=d), B=P^T (col=q)
#pragma unroll
            for (int ks = 0; ks < 4; ++ks) {
                bf16x8 vf0 = *(const bf16x8*)&Vtp[(lq)      * 72 + ks * 16 + hi * 8];
                bf16x8 vf1 = *(const bf16x8*)&Vtp[(32 + lq) * 72 + ks * 16 + hi * 8];
                o0 = mfma32(vf0, pb[ks], o0);
                o1 = mfma32(vf1, pb[ks], o1);
            }
        }
        __syncthreads();   // all reads done before next step's staging
    }

    // ---- merge pair B into pair A (lane-aligned: same lane = same q)
    float* obase = (float*)pool;                       // [2][64*33]
    float* mlb   = (float*)pool + 2 * 64 * 33 + half * 64;  // [m:32][l:32]
    if (pa == 1) {
        float* ob = obase + half * (64 * 33) + lane * 33;
#pragma unroll
        for (int r = 0; r < 16; ++r) { ob[r] = o0[r]; ob[16 + r] = o1[r]; }
        if (hi == 0) { mlb[lq] = m_i; mlb[32 + lq] = l_i; }
    }
    __syncthreads();
    if (pa == 0) {
        const float mB = mlb[lq], lB = mlb[32 + lq];
        const float* ob = obase + half * (64 * 33) + lane * 33;
        const float mm = fmaxf(m_i, mB);
        const float sA = __builtin_amdgcn_exp2f((m_i - mm) * cexp);
        const float sB = __builtin_amdgcn_exp2f((mB  - mm) * cexp);
        const float inv = 1.0f / (l_i * sA + lB * sB);
        u16* yrow = Yb + (rb + q0w + lq) * DD + hoff;
#pragma unroll
        for (int g = 0; g < 4; ++g) {
            u16x4 p0, p1;
#pragma unroll
            for (int j = 0; j < 4; ++j) {
                p0[j] = f2bf((o0[4 * g + j] * sA + ob[4 * g + j]      * sB) * inv);
                p1[j] = f2bf((o1[4 * g + j] * sA + ob[16 + 4 * g + j] * sB) * inv);
            }
            *(u16x4*)&yrow[8 * g + 4 * hi]      = p0;
            *(u16x4*)&yrow[32 + 8 * g + 4 * hi] = p1;
        }
    }
}

// ------------------------------- launcher ----------------------------------
extern "C" void kernel_launch(void* const* d_in, const int* in_sizes, int n_in,
                              void* d_out, int out_size, void* d_ws, size_t ws_size,
                              hipStream_t stream) {
    const float* x  = (const float*)d_in[0];
    const float* Wq = (const float*)d_in[1];
    const float* bq = (const float*)d_in[2];
    const float* Wk = (const float*)d_in[3];
    const float* bk = (const float*)d_in[4];
    const float* Wv = (const float*)d_in[5];
    const float* bv = (const float*)d_in[6];
    const float* Wo = (const float*)d_in[7];
    const float* bo = (const float*)d_in[8];
    float* out = (float*)d_out;

    const size_t XN = (size_t)MM * DD;   // 4,194,304
    const size_t WN = (size_t)DD * DD;   // 1,048,576

    u16* xb  = (u16*)d_ws;
    u16* Wb  = xb  + XN;          // Wq,Wk,Wv stacked: 3*WN
    u16* Wob = Wb  + 3 * WN;
    u16* QKV = Wob + WN;          // Q,K,V stacked: 3*XN
    u16* Yb  = QKV + 3 * XN;

    cvt_kernel<<<2048, 256, 0, stream>>>(x, xb, (int)(XN / 4));
    cvt4_kernel<<<dim3(256, 4), 256, 0, stream>>>(Wq, Wk, Wv, Wo,
            Wb, Wb + WN, Wb + 2 * WN, Wob, (int)(WN / 4));

    gemm_nt<0><<<dim3(32, 8, 3), 256, 0, stream>>>(xb, Wb, bq, bk, bv,
                                                   QKV, nullptr, MM, DD, DD);
    attn_kernel<<<dim3(32, BB * HH), 256, 0, stream>>>(QKV, QKV + XN,
                                                       QKV + 2 * XN, Yb);
    gemm_nt<1><<<dim3(32, 8, 1), 256, 0, stream>>>(Yb, Wob, bo, bo, bo,
                                                   nullptr, out, MM, DD, DD);
}

// Round 5
// 156.846 us; speedup vs baseline: 1.3356x; 1.3356x over previous
//
#include <hip/hip_runtime.h>
#include <stdint.h>

// ---------------------------------------------------------------------------
// CausalSelfAttention (B=2, T=2048, D=1024, H=16, Dh=64), fp32 in/out.
// cvt(fp32->bf16) -> QKV gemm (bf16 MFMA) -> flash attn (32x32 swapped,
// in-block KV-split pairs, K via global_load_lds) -> out gemm.
// ---------------------------------------------------------------------------

typedef unsigned short u16;
typedef __attribute__((ext_vector_type(8)))  __bf16 bf16x8;   // 4 VGPR MFMA A/B frag
typedef __attribute__((ext_vector_type(4)))  float  f32x4;    // 16x16 C/D frag
typedef __attribute__((ext_vector_type(16))) float  f32x16;   // 32x32 C/D frag
typedef __attribute__((ext_vector_type(4)))  float  float4v;
typedef __attribute__((ext_vector_type(4)))  unsigned short u16x4;
typedef __attribute__((ext_vector_type(4)))  unsigned int   u32x4;
typedef __attribute__((ext_vector_type(8)))  short  short8;   // raw 16B load

#define BB 2
#define TT 2048
#define DD 1024
#define HH 16
#define DH 64
#define MM (BB*TT)          // 4096 rows

static __device__ __forceinline__ u16 f2bf(float f) {
    uint32_t u = __builtin_bit_cast(uint32_t, f);
    u += 0x7FFFu + ((u >> 16) & 1u);          // round-to-nearest-even
    return (u16)(u >> 16);
}

// pack two f32 -> one u32 of two bf16 (low = a, high = b)
static __device__ __forceinline__ unsigned cvt_pk_bf16(float a, float b) {
    unsigned r;
    asm("v_cvt_pk_bf16_f32 %0, %1, %2" : "=v"(r) : "v"(a), "v"(b));
    return r;
}

// global(16B per lane) -> LDS direct copy (wave-uniform dst base + lane*16).
static __device__ __forceinline__ void load_lds16(const u16* g, const u16* lds_base) {
    __builtin_amdgcn_global_load_lds(
        (const __attribute__((address_space(1))) void*)(uintptr_t)g,
        (__attribute__((address_space(3)))  void*)(uint32_t)(uintptr_t)lds_base,
        16u, 0, 0u);
}

static __device__ __forceinline__ f32x4 mfma16(bf16x8 a, bf16x8 b, f32x4 c) {
    return __builtin_amdgcn_mfma_f32_16x16x32_bf16(a, b, c, 0, 0, 0);
}
static __device__ __forceinline__ f32x16 mfma32(bf16x8 a, bf16x8 b, f32x16 c) {
    return __builtin_amdgcn_mfma_f32_32x32x16_bf16(a, b, c, 0, 0, 0);
}

// balanced trees over the 32 per-lane score registers (depth ~5, not 31)
static __device__ __forceinline__ float tree_max32(const f32x16& a, const f32x16& b) {
    float m[16];
#pragma unroll
    for (int r = 0; r < 16; ++r) m[r] = fmaxf(a[r], b[r]);
#pragma unroll
    for (int off = 8; off; off >>= 1)
#pragma unroll
        for (int r = 0; r < off; ++r) m[r] = fmaxf(m[r], m[r + off]);
    return m[0];
}
static __device__ __forceinline__ float tree_sum32(const f32x16& a, const f32x16& b) {
    float m[16];
#pragma unroll
    for (int r = 0; r < 16; ++r) m[r] = a[r] + b[r];
#pragma unroll
    for (int off = 8; off; off >>= 1)
#pragma unroll
        for (int r = 0; r < off; ++r) m[r] += m[r + off];
    return m[0];
}

// ------------------------------ fp32 -> bf16 -------------------------------
__global__ __launch_bounds__(256) void cvt_kernel(const float* __restrict__ src,
                                                  u16* __restrict__ dst, int n4) {
    int i = blockIdx.x * blockDim.x + threadIdx.x;
    int stride = gridDim.x * blockDim.x;
    for (; i < n4; i += stride) {
        float4v v = ((const float4v*)src)[i];
        u16x4 o;
        o[0] = f2bf(v[0]); o[1] = f2bf(v[1]); o[2] = f2bf(v[2]); o[3] = f2bf(v[3]);
        ((u16x4*)dst)[i] = o;
    }
}

// four matrices in one launch (z = blockIdx.y selects)
__global__ __launch_bounds__(256) void cvt4_kernel(const float* __restrict__ s0,
        const float* __restrict__ s1, const float* __restrict__ s2,
        const float* __restrict__ s3, u16* __restrict__ d0, u16* __restrict__ d1,
        u16* __restrict__ d2, u16* __restrict__ d3, int n4) {
    const int z = blockIdx.y;
    const float* src = (z == 0) ? s0 : (z == 1) ? s1 : (z == 2) ? s2 : s3;
    u16* dst = (z == 0) ? d0 : (z == 1) ? d1 : (z == 2) ? d2 : d3;
    int i = blockIdx.x * blockDim.x + threadIdx.x;
    int stride = gridDim.x * blockDim.x;
    for (; i < n4; i += stride) {
        float4v v = ((const float4v*)src)[i];
        u16x4 o;
        o[0] = f2bf(v[0]); o[1] = f2bf(v[1]); o[2] = f2bf(v[2]); o[3] = f2bf(v[3]);
        ((u16x4*)dst)[i] = o;
    }
}

// ------------------------- GEMM  C = A * W^T + bias ------------------------
// A: [M,K] bf16 row-major. W: [z][N,K] bf16 row-major (z = blockIdx.z).
// OUTF32==0: bf16 out at outb + z*M*N ; OUTF32==1: f32 out to outf.
// 128x128 tile, BK=32, 256 threads (4 waves, 2x2 of 64x64), m97 structure.
template<int OUTF32>
__global__ __launch_bounds__(256) void gemm_nt(const u16* __restrict__ A,
        const u16* __restrict__ W,
        const float* __restrict__ b0, const float* __restrict__ b1,
        const float* __restrict__ b2,
        u16* __restrict__ outb, float* __restrict__ outf,
        int M, int N, int K) {
    __shared__ alignas(16) u16 As[128 * 32];
    __shared__ alignas(16) u16 Bs[128 * 32];

    const int tid  = threadIdx.x;
    const int wave = tid >> 6, lane = tid & 63;
    const int lr = lane & 15, lg = lane >> 4;
    const int wr = wave >> 1, wc = wave & 1;
    const int z  = blockIdx.z;
    const int m0 = blockIdx.x * 128;
    const int n0 = blockIdx.y * 128;

    const u16* Wz = W + (size_t)z * N * K;
    const float* bias = (z == 0) ? b0 : (z == 1) ? b1 : b2;

    f32x4 acc[4][4];
#pragma unroll
    for (int m = 0; m < 4; ++m)
#pragma unroll
        for (int n = 0; n < 4; ++n) acc[m][n] = (f32x4){0.f, 0.f, 0.f, 0.f};

    for (int k0 = 0; k0 < K; k0 += 32) {
        __syncthreads();
#pragma unroll
        for (int it = 0; it < 2; ++it) {
            int c = it * 256 + tid;
            int row = c >> 2, cc = (c & 3) * 8;
            const u16* gA = A  + (size_t)(m0 + row) * K + k0 + cc;
            const u16* gB = Wz + (size_t)(n0 + row) * K + k0 + cc;
            load_lds16(gA, As + (size_t)(it * 256 + wave * 64) * 8);
            load_lds16(gB, Bs + (size_t)(it * 256 + wave * 64) * 8);
        }
        __syncthreads();

        bf16x8 af[4], bfm[4];
#pragma unroll
        for (int m = 0; m < 4; ++m)
            af[m] = *(const bf16x8*)&As[(wr * 64 + m * 16 + lr) * 32 + lg * 8];
#pragma unroll
        for (int n = 0; n < 4; ++n)
            bfm[n] = *(const bf16x8*)&Bs[(wc * 64 + n * 16 + lr) * 32 + lg * 8];
#pragma unroll
        for (int m = 0; m < 4; ++m)
#pragma unroll
            for (int n = 0; n < 4; ++n)
                acc[m][n] = mfma16(af[m], bfm[n], acc[m][n]);
    }

#pragma unroll
    for (int n = 0; n < 4; ++n) {
        int col = n0 + wc * 64 + n * 16 + lr;
        float bv = bias[col];
#pragma unroll
        for (int m = 0; m < 4; ++m) {
            int row = m0 + wr * 64 + m * 16 + lg * 4;
#pragma unroll
            for (int r = 0; r < 4; ++r) {
                float v = acc[m][n][r] + bv;
                if (OUTF32 == 0)
                    outb[(size_t)z * M * N + (size_t)(row + r) * N + col] = f2bf(v);
                else
                    outf[(size_t)(row + r) * N + col] = v;
            }
        }
    }
}

// ------------------------------- attention ---------------------------------
// grid (32, 32): qb = 31 - blockIdx.x, 64 q rows per block; bh = blockIdx.y.
// 4 warps = 2 pairs. Pair pa (= wave>>1) processes tiles t = 2s+pa (KV-split);
// half (= wave&1) picks the 32-q-row slice. Private online-softmax state per
// pair; one in-LDS merge at the end (paired warps own the SAME q columns).
// Swapped-operand 32x32 MFMA: S^T = K.Q^T (lane owns one q col). K staged via
// global_load_lds into a per-pair swizzled LDS buffer (coalesced); V reg->LDS
// transposed per pair. 2 barriers per step; 4 blocks/CU.
__global__ __launch_bounds__(256, 4) void attn_kernel(const u16* __restrict__ Qb,
        const u16* __restrict__ Kb, const u16* __restrict__ Vb,
        u16* __restrict__ Yb) {
    // loop phase: Ks[2][64*64] (16 KB) + Vt[2][64*72] (18 KB)
    // merge phase overlay on Ks+Vt: Ob f32[2][64*33] + Ml f32[2][64] (17.4 KB)
    __shared__ alignas(16) u16 Ks[2][64 * 64];
    __shared__ alignas(16) u16 Vt[2][64 * 72];

    const int tid  = threadIdx.x;
    const int wave = tid >> 6, lane = tid & 63;
    const int lq = lane & 31, hi = lane >> 5;
    const int pa   = wave >> 1;               // 0: even tiles, 1: odd tiles
    const int half = wave & 1;                // q half within the block
    const int qb = 31 - blockIdx.x;           // longest blocks dispatch first
    const int bh = blockIdx.y;
    const int b = bh >> 4, h = bh & 15;
    const size_t rb = (size_t)b * TT;
    const int hoff = h * DH;
    const int q0w = qb * 64 + half * 32;      // warp q base (within this b)
    const int nk = qb + 1;                    // 64-key tiles needed by block
    const int steps = (nk + 1) >> 1;

    u16* Ksp = Ks[pa];
    u16* Vtp = Vt[pa];
    const u16* Kbh = Kb + rb * DD + hoff;
    const u16* Vbh = Vb + rb * DD + hoff;

    // K staging: this wave covers chunks c = half*256 + it*64 + lane, it=0..3
    // V staging: lane = key, half picks d range
    const int vkey = lane;
    const int vd0  = half * 32;

    // Q fragments (B-operand): col=lane&31=q, k=(lane>>5)*8+j ; 4 chunks of 16
    bf16x8 qf[4];
    {
        const u16* qrow = Qb + (rb + q0w + lq) * DD + hoff + hi * 8;
#pragma unroll
        for (int kc = 0; kc < 4; ++kc) qf[kc] = *(const bf16x8*)(qrow + kc * 16);
    }

    f32x16 o0 = {}, o1 = {};
    float m_i = -1e30f, l_i = 0.f;
    const float cexp = 0.18033688011f;        // 0.125 * log2(e)

    for (int s = 0; s < steps; ++s) {
        const int t  = 2 * s + pa;            // this pair's tile this step
        const int tc = (t < nk) ? t : nk - 1; // clamp staging addr (odd-nk edge)
        const u16* Kt = Kbh + (size_t)tc * 64 * DD;

        // ---- stage K via global_load_lds (swizzled source, linear LDS dest)
#pragma unroll
        for (int it = 0; it < 4; ++it) {
            int c = half * 256 + it * 64 + lane;
            int row = c >> 3, sl = c & 7;
            load_lds16(Kt + (size_t)row * DD + (sl ^ (row & 7)) * 8,
                       Ksp + (size_t)(half * 256 + it * 64) * 8);
        }
        // ---- stage V^T (reg -> LDS transpose)
        {
            const u16* vrow = Vbh + (size_t)(tc * 64 + vkey) * DD + vd0;
            short8 v0 = *(const short8*)(vrow);
            short8 v1 = *(const short8*)(vrow + 8);
            short8 v2 = *(const short8*)(vrow + 16);
            short8 v3 = *(const short8*)(vrow + 24);
#pragma unroll
            for (int j = 0; j < 8; ++j) {
                Vtp[(vd0 +      j) * 72 + vkey] = (u16)v0[j];
                Vtp[(vd0 +  8 + j) * 72 + vkey] = (u16)v1[j];
                Vtp[(vd0 + 16 + j) * 72 + vkey] = (u16)v2[j];
                Vtp[(vd0 + 24 + j) * 72 + vkey] = (u16)v3[j];
            }
        }
        __syncthreads();

        if (t < nk) {
            // S^T[key][q] = K.Q^T : A=K (row=key, swizzled read), B=Q (col=q)
            f32x16 st0 = {}, st1 = {};
            const int rowm = lq & 7;
#pragma unroll
            for (int kc = 0; kc < 4; ++kc) {
                bf16x8 k0 = *(const bf16x8*)&Ksp[(lq)      * 64 + ((2 * kc + hi) ^ rowm) * 8];
                st0 = mfma32(k0, qf[kc], st0);
            }
#pragma unroll
            for (int kc = 0; kc < 4; ++kc) {
                bf16x8 k1 = *(const bf16x8*)&Ksp[(32 + lq) * 64 + ((2 * kc + hi) ^ rowm) * 8];
                st1 = mfma32(k1, qf[kc], st1);
            }

            // causal mask on raw scores (scale folded into exp2 constant)
            if (t * 64 + 63 > q0w) {
                const int qrel = q0w + lq - t * 64;
#pragma unroll
                for (int r = 0; r < 16; ++r) {
                    int key = (r & 3) + 8 * (r >> 2) + 4 * hi;
                    if (key      > qrel) st0[r] = -1e30f;
                    if (key + 32 > qrel) st1[r] = -1e30f;
                }
            }

            // online softmax, in-lane tree reduces
            float pm = tree_max32(st0, st1);
            pm = fmaxf(pm, __shfl_xor(pm, 32));
            if (!__all(pm - m_i <= 44.3614f)) {      // defer-max (T13)
                const float mnew  = fmaxf(m_i, pm);
                const float alpha = __builtin_amdgcn_exp2f((m_i - mnew) * cexp);
                l_i *= alpha;
#pragma unroll
                for (int r = 0; r < 16; ++r) { o0[r] *= alpha; o1[r] *= alpha; }
                m_i = mnew;
            }
#pragma unroll
            for (int r = 0; r < 16; ++r) {
                st0[r] = __builtin_amdgcn_exp2f((st0[r] - m_i) * cexp);
                st1[r] = __builtin_amdgcn_exp2f((st1[r] - m_i) * cexp);
            }
            float rs = tree_sum32(st0, st1);
            rs += __shfl_xor(rs, 32);
            l_i += rs;

            // P^T -> B-operand frags: cvt_pk pairs + permlane32_swap (T12)
            bf16x8 pb[4];
#pragma unroll
            for (int ks = 0; ks < 4; ++ks) {
                const f32x16& sb = (ks < 2) ? st0 : st1;
                const int base = 8 * (ks & 1);
                unsigned c0 = cvt_pk_bf16(sb[base + 0], sb[base + 1]);
                unsigned c1 = cvt_pk_bf16(sb[base + 2], sb[base + 3]);
                unsigned c2 = cvt_pk_bf16(sb[base + 4], sb[base + 5]);
                unsigned c3 = cvt_pk_bf16(sb[base + 6], sb[base + 7]);
                asm volatile("v_permlane32_swap_b32 %0, %1" : "+v"(c0), "+v"(c2));
                asm volatile("v_permlane32_swap_b32 %0, %1" : "+v"(c1), "+v"(c3));
                u32x4 w; w[0] = c0; w[1] = c1; w[2] = c2; w[3] = c3;
                pb[ks] = __builtin_bit_cast(bf16x8, w);
            }

            // O^T += V^T . P^T : A=V^T (row=d), B=P^T (col=q)
#pragma unroll
            for (int ks = 0; ks < 4; ++ks) {
                bf16x8 vf0 = *(const bf16x8*)&Vtp[(lq)      * 72 + ks * 16 + hi * 8];
                bf16x8 vf1 = *(const bf16x8*)&Vtp[(32 + lq) * 72 + ks * 16 + hi * 8];
                o0 = mfma32(vf0, pb[ks], o0);
                o1 = mfma32(vf1, pb[ks], o1);
            }
        }
        __syncthreads();   // all reads done before next step's staging
    }

    // ---- merge pair B into pair A (lane-aligned: same lane = same q)
    float* obase = (float*)&Ks[0][0];                       // [2][64*33]
    float* mlb   = (float*)&Ks[0][0] + 2 * 64 * 33 + half * 64;  // [m:32][l:32]
    if (pa == 1) {
        float* ob = obase + half * (64 * 33) + lane * 33;
#pragma unroll
        for (int r = 0; r < 16; ++r) { ob[r] = o0[r]; ob[16 + r] = o1[r]; }
        if (hi == 0) { mlb[lq] = m_i; mlb[32 + lq] = l_i; }
    }
    __syncthreads();
    if (pa == 0) {
        const float mB = mlb[lq], lB = mlb[32 + lq];
        const float* ob = obase + half * (64 * 33) + lane * 33;
        const float mm = fmaxf(m_i, mB);
        const float sA = __builtin_amdgcn_exp2f((m_i - mm) * cexp);
        const float sB = __builtin_amdgcn_exp2f((mB  - mm) * cexp);
        const float inv = 1.0f / (l_i * sA + lB * sB);
        u16* yrow = Yb + (rb + q0w + lq) * DD + hoff;
#pragma unroll
        for (int g = 0; g < 4; ++g) {
            u16x4 p0, p1;
#pragma unroll
            for (int j = 0; j < 4; ++j) {
                p0[j] = f2bf((o0[4 * g + j] * sA + ob[4 * g + j]      * sB) * inv);
                p1[j] = f2bf((o1[4 * g + j] * sA + ob[16 + 4 * g + j] * sB) * inv);
            }
            *(u16x4*)&yrow[8 * g + 4 * hi]      = p0;
            *(u16x4*)&yrow[32 + 8 * g + 4 * hi] = p1;
        }
    }
}

// ------------------------------- launcher ----------------------------------
extern "C" void kernel_launch(void* const* d_in, const int* in_sizes, int n_in,
                              void* d_out, int out_size, void* d_ws, size_t ws_size,
                              hipStream_t stream) {
    const float* x  = (const float*)d_in[0];
    const float* Wq = (const float*)d_in[1];
    const float* bq = (const float*)d_in[2];
    const float* Wk = (const float*)d_in[3];
    const float* bk = (const float*)d_in[4];
    const float* Wv = (const float*)d_in[5];
    const float* bv = (const float*)d_in[6];
    const float* Wo = (const float*)d_in[7];
    const float* bo = (const float*)d_in[8];
    float* out = (float*)d_out;

    const size_t XN = (size_t)MM * DD;   // 4,194,304
    const size_t WN = (size_t)DD * DD;   // 1,048,576

    u16* xb  = (u16*)d_ws;
    u16* Wb  = xb  + XN;          // Wq,Wk,Wv stacked: 3*WN
    u16* Wob = Wb  + 3 * WN;
    u16* QKV = Wob + WN;          // Q,K,V stacked: 3*XN
    u16* Yb  = QKV + 3 * XN;

    cvt_kernel<<<2048, 256, 0, stream>>>(x, xb, (int)(XN / 4));
    cvt4_kernel<<<dim3(256, 4), 256, 0, stream>>>(Wq, Wk, Wv, Wo,
            Wb, Wb + WN, Wb + 2 * WN, Wob, (int)(WN / 4));

    gemm_nt<0><<<dim3(32, 8, 3), 256, 0, stream>>>(xb, Wb, bq, bk, bv,
                                                   QKV, nullptr, MM, DD, DD);
    attn_kernel<<<dim3(32, BB * HH), 256, 0, stream>>>(QKV, QKV + XN,
                                                       QKV + 2 * XN, Yb);
    gemm_nt<1><<<dim3(32, 8, 1), 256, 0, stream>>>(Yb, Wob, bo, bo, bo,
                                                   nullptr, out, MM, DD, DD);
}